// Round 12
// baseline (347.724 us; speedup 1.0000x reference)
//
#include <hip/hip_runtime.h>
#include <cstdint>
#include <cstddef>

#define Bn 64
#define Sn 512
#define Hn 768
#define Tn 50
#define CH 32   // scan chunk length (steps)
#define NCH 16  // max chunks per sequence
#define EP 52   // padded row stride for exp(trans) tables
#define BK 64

// Measurement round: every kernel body is idempotent, so we loop it REP_*
// times in-kernel (memory clobber prevents hoisting). Outputs identical;
// per-dispatch duration = REP * true cost -> visible in rocprof top-5.
#define REP_PREP 16
#define REP_EM 8
#define REP_SCAN 8
#define REP_STITCH 16

typedef short short8 __attribute__((ext_vector_type(8)));
typedef float floatx4 __attribute__((ext_vector_type(4)));

__device__ __forceinline__ uint32_t rne_bf16(float x) {
  uint32_t u = __float_as_uint(x);
  return (u + 0x7FFFu + ((u >> 16) & 1u)) >> 16;
}
__device__ __forceinline__ uint32_t pack2(float a, float b) {
  return rne_bf16(a) | (rne_bf16(b) << 16);
}
__device__ __forceinline__ float rdlane(float v, int i) {
  return __uint_as_float(__builtin_amdgcn_readlane(__float_as_uint(v), i));
}

// ------ Kernel 0: prep (r6 body, x16) ------
__global__ __launch_bounds__(256) void prep_kernel(
    const float* __restrict__ W, const float* __restrict__ trans,
    const int* __restrict__ mask, uint32_t* __restrict__ wfrag,
    int* __restrict__ lenbuf, float* __restrict__ Ee,
    float* __restrict__ EeT) {
  const int blk = blockIdx.x;
  const int tid = threadIdx.x;
  for (int rep = 0; rep < REP_PREP; ++rep) {
    if (blk < 64) {
      if (tid < 64) {
        int s = 0;
        for (int t = tid; t < Sn; t += 64) s += mask[blk * Sn + t];
#pragma unroll
        for (int off = 1; off < 64; off <<= 1) s += __shfl_xor(s, off);
        if (tid == 0) lenbuf[blk] = s;
      }
    } else if (blk == 88) {
      for (int gid = tid; gid < Tn * Tn; gid += 256) {
        const int r = gid / Tn, cl = gid - r * Tn;
        const float v = __expf(trans[gid]);
        Ee[r * EP + cl] = v;
        EeT[cl * EP + r] = v;
      }
    } else {
      const int gid = (blk - 64) * 256 + tid;  // [0, 6144)
      const int f = gid >> 6;
      const int l = gid & 63;
      const int ks = f >> 2, nt = f & 3;
      const int col = nt * 16 + (l & 15);
      const int k0 = ks * 32 + (l >> 4) * 8;
      float v[8];
#pragma unroll
      for (int j = 0; j < 8; ++j)
        v[j] = (col < Tn) ? W[(size_t)(k0 + j) * Tn + col] : 0.f;
      uint4 d;
      d.x = pack2(v[0], v[1]);
      d.y = pack2(v[2], v[3]);
      d.z = pack2(v[4], v[5]);
      d.w = pack2(v[6], v[7]);
      ((uint4*)wfrag)[gid] = d;
    }
    asm volatile("" ::: "memory");
  }
}

// ------ Kernel 1: emissions via MFMA (r6 body, (256,1), x8) ------
__global__ __launch_bounds__(256, 1) void emissions_kernel(
    const float* __restrict__ hidden, const uint32_t* __restrict__ wfrag,
    const float* __restrict__ bias, const int* __restrict__ lenbuf,
    float* __restrict__ em) {
  const int blk = blockIdx.x;
  const int bb = blk >> 3, cc = blk & 7;
  if (cc * 64 >= lenbuf[bb]) return;  // rows never read by CRF
  const int tid = threadIdx.x;
  const int lane = tid & 63;
  const int w = tid >> 6;
  const int g = lane >> 4;
  const int li = lane & 15;
  const int row0 = blk * 64;
  __shared__ char lds_raw[64 * 128];

  for (int rep = 0; rep < REP_EM; ++rep) {
    floatx4 acc[4];
#pragma unroll
    for (int nt = 0; nt < 4; ++nt) acc[nt] = (floatx4)0.f;

    const float* hbase = hidden + (size_t)row0 * Hn;
    const short8* wf = (const short8*)wfrag;

#define LOADCH(dst, ch)                                                      \
  _Pragma("unroll") for (int k = 0; k < 4; ++k) dst[k] =                     \
      *(const float4*)(hbase + (size_t)(w * 16 + 4 * k + g) * Hn + (ch)*BK + \
                       li * 4);
#define WRITELDS(src)                                                        \
  _Pragma("unroll") for (int k = 0; k < 4; ++k) {                            \
    const int r = w * 16 + 4 * k + g;                                        \
    const uint32_t b0 = pack2(src[k].x, src[k].y);                           \
    const uint32_t b1 = pack2(src[k].z, src[k].w);                           \
    const int byteoff = r * 128 + ((li * 8) ^ ((r & 7) << 4));               \
    *(uint2*)(lds_raw + byteoff) = make_uint2(b0, b1);                       \
  }
#define COMPUTE(ch)                                                          \
  _Pragma("unroll") for (int ks = 0; ks < 2; ++ks) {                         \
    const int r = w * 16 + li;                                               \
    const int kb = ks * 64 + g * 16;                                         \
    const short8 af =                                                        \
        *(const short8*)(lds_raw + r * 128 + (kb ^ ((r & 7) << 4)));         \
    const int ksg = (ch)*2 + ks;                                             \
    _Pragma("unroll") for (int nt = 0; nt < 4; ++nt) {                       \
      const short8 bf = wf[(ksg * 4 + nt) * 64 + lane];                      \
      acc[nt] =                                                              \
          __builtin_amdgcn_mfma_f32_16x16x32_bf16(af, bf, acc[nt], 0, 0, 0); \
    }                                                                        \
  }

    float4 pfA[4], pfB[4];
    LOADCH(pfA, 0)
    LOADCH(pfB, 1)
#pragma unroll
    for (int chp = 0; chp < Hn / BK / 2; ++chp) {
      const int ch = 2 * chp;
      WRITELDS(pfA)
      if (ch + 2 < Hn / BK) LOADCH(pfA, ch + 2)
      COMPUTE(ch)
      WRITELDS(pfB)
      if (ch + 3 < Hn / BK) LOADCH(pfB, ch + 3)
      COMPUTE(ch + 1)
    }
#undef LOADCH
#undef WRITELDS
#undef COMPUTE

#pragma unroll
    for (int nt = 0; nt < 4; ++nt) {
      const int col = nt * 16 + li;
      if (col < Tn) {
        const float bs = bias[col];
#pragma unroll
        for (int r = 0; r < 4; ++r) {
          const int row = row0 + w * 16 + g * 4 + r;
          em[(size_t)row * Tn + col] = acc[nt][r] + bs;
        }
      }
    }
    asm volatile("" ::: "memory");
    __syncthreads();
  }
}

// ------ Kernel 2: chunked scans (r6 body, x8) ------
__global__ __launch_bounds__(64, 1) void scan_kernel(
    const float* __restrict__ em, const float* __restrict__ startT,
    const float* __restrict__ trans, const float* __restrict__ Ee,
    const float* __restrict__ EeT, const int* __restrict__ tag,
    const int* __restrict__ lenbuf, float* __restrict__ fvec,
    float* __restrict__ gvec, float* __restrict__ Lf,
    float* __restrict__ numpart) {
  const int blk = blockIdx.x;
  const int b = blk >> 5;
  const int c = (blk >> 1) & (NCH - 1);
  const int dir = blk & 1;
  const int len = lenbuf[b];
  const int t0 = 1 + c * CH;
  if (t0 >= len) return;
  if (dir && c == 0) return;
  const int t1 = (t0 + CH < len) ? t0 + CH : len;
  const int L = t1 - t0;
  const int lane = threadIdx.x;
  const int jc = lane < Tn ? lane : 0;
  const bool live = lane < Tn;
  const float* emb = em + (size_t)b * Sn * Tn;

  for (int rep = 0; rep < REP_SCAN; ++rep) {
    if (!dir) {  // chunk numerator partial
      float npv = 0.f;
      if (lane < L) {
        const int t = t0 + lane;
        const int tp = tag[b * Sn + t - 1], tc = tag[b * Sn + t];
        npv = trans[tp * Tn + tc] + emb[(size_t)t * Tn + tc];
      }
#pragma unroll
      for (int off = 1; off < 64; off <<= 1) npv += __shfl_xor(npv, off);
      if (lane == 0) numpart[b * NCH + c] = npv;
    }

    const float* ebase = (dir ? Ee : EeT) + jc * EP;
    float e[Tn];
#pragma unroll
    for (int i = 0; i < Tn; ++i) e[i] = ebase[i];

    float Cacc = 0.f;
    float q;
    if (!dir)
      q = live ? (c == 0 ? __expf(startT[jc] + emb[jc]) : 1.f) : 0.f;
    else
      q = live ? 1.f : 0.f;

#define T_OF(k) (dir ? (t1 - 1 - (k)) : (t0 + (k)))
    float ld1 = emb[(size_t)T_OF(0) * Tn + jc];
    const float ld2 = emb[(size_t)T_OF(L > 1 ? 1 : 0) * Tn + jc];
    float ee = live ? __expf(ld1) : 0.f;
    ld1 = ld2;

    for (int k = 0; k < L; ++k) {
      const float ee_cur = ee;
      const int kn = (k + 2 < L) ? k + 2 : L - 1;
      const float ldn = emb[(size_t)T_OF(kn) * Tn + jc];
      ee = live ? __expf(ld1) : 0.f;
      ld1 = ldn;

      const float x = dir ? ee_cur * q : q;
      float s0 = 0.f, s1 = 0.f, s2 = 0.f, s3 = 0.f;
#pragma unroll
      for (int i = 0; i < 48; i += 4) {
        s0 = fmaf(rdlane(x, i + 0), e[i + 0], s0);
        s1 = fmaf(rdlane(x, i + 1), e[i + 1], s1);
        s2 = fmaf(rdlane(x, i + 2), e[i + 2], s2);
        s3 = fmaf(rdlane(x, i + 3), e[i + 3], s3);
      }
      s0 = fmaf(rdlane(x, 48), e[48], s0);
      s1 = fmaf(rdlane(x, 49), e[49], s1);
      const float s = (s0 + s1) + (s2 + s3);
      q = dir ? s : ee_cur * s;

      if ((k & 7) == 7) {
        float M = q;
#pragma unroll
        for (int off = 1; off < 64; off <<= 1) M = fmaxf(M, __shfl_xor(M, off));
        const float r = __builtin_amdgcn_rcpf(M);
        q *= r;
        Cacc -= __logf(r);
      }
    }
#undef T_OF

    float M = q;
#pragma unroll
    for (int off = 1; off < 64; off <<= 1) M = fmaxf(M, __shfl_xor(M, off));
    const float r = __builtin_amdgcn_rcpf(M);
    const float qn = live ? q * r : 0.f;
    Cacc -= __logf(r);
    if (dir) {
      gvec[((size_t)b * NCH + c) * 64 + lane] = qn;
    } else {
      fvec[((size_t)b * NCH + c) * 64 + lane] = qn;
      if (lane == 0) Lf[b * NCH + c] = Cacc;
    }
    asm volatile("" ::: "memory");
  }
}

// ------ Kernel 3: stitch (r6 body, x16) ------
__global__ __launch_bounds__(64) void stitch_kernel(
    const float* __restrict__ em, const float* __restrict__ startT,
    const float* __restrict__ endT, const int* __restrict__ tag,
    const int* __restrict__ lenbuf, const float* __restrict__ fvec,
    const float* __restrict__ gvec, const float* __restrict__ Lf,
    const float* __restrict__ numpart, float* __restrict__ out) {
  const int b = blockIdx.x;
  const int lane = threadIdx.x;
  const int len = lenbuf[b];
  const int C = (len - 1 + CH - 1) / CH;
  const int jc = lane < Tn ? lane : 0;
  const bool live = lane < Tn;
  const float* emb = em + (size_t)b * Sn * Tn;

  for (int rep = 0; rep < REP_STITCH; ++rep) {
    float np = (lane < C) ? numpart[b * NCH + lane] : 0.f;
#pragma unroll
    for (int off = 1; off < 64; off <<= 1) np += __shfl_xor(np, off);
    const int tg0 = tag[b * Sn];
    const int tgl = tag[b * Sn + len - 1];
    np += startT[tg0] + emb[tg0] + endT[tgl];

    float den;
    if (C == 0) {
      float v = live ? (startT[jc] + emb[jc] + endT[jc]) : -INFINITY;
      float M = v;
#pragma unroll
      for (int off = 1; off < 64; off <<= 1) M = fmaxf(M, __shfl_xor(M, off));
      float s = __expf(v - M);
#pragma unroll
      for (int off = 1; off < 64; off <<= 1) s += __shfl_xor(s, off);
      den = M + __logf(s);
    } else {
      const float ev = live ? __expf(endT[jc]) : 0.f;
      float d = fvec[((size_t)b * NCH + C - 1) * 64 + lane] * ev;
#pragma unroll
      for (int off = 1; off < 64; off <<= 1) d += __shfl_xor(d, off);
      den = Lf[b * NCH + C - 1] + __logf(d);
      for (int c2 = 1; c2 < C; ++c2) {
        const float g = gvec[((size_t)b * NCH + c2) * 64 + lane];
        const float f = fvec[((size_t)b * NCH + c2 - 1) * 64 + lane];
        float dot = g * f;
        float gs = g;
#pragma unroll
        for (int off = 1; off < 64; off <<= 1) {
          dot += __shfl_xor(dot, off);
          gs += __shfl_xor(gs, off);
        }
        den += Lf[b * NCH + c2 - 1] + __logf(dot) - __logf(gs);
      }
    }
    if (lane == 0) out[b] = den - np;
    asm volatile("" ::: "memory");
  }
}

extern "C" void kernel_launch(void* const* d_in, const int* in_sizes, int n_in,
                              void* d_out, int out_size, void* d_ws,
                              size_t ws_size, hipStream_t stream) {
  const float* hidden = (const float*)d_in[0];
  const float* W = (const float*)d_in[1];
  const float* bias = (const float*)d_in[2];
  const float* startT = (const float*)d_in[3];
  const float* endT = (const float*)d_in[4];
  const float* trans = (const float*)d_in[5];
  const int* tag = (const int*)d_in[6];
  const int* mask = (const int*)d_in[7];
  float* out = (float*)d_out;

  // ws layout (16B-aligned offsets) — r6 layout
  char* ws = (char*)d_ws;
  float* em = (float*)ws;                       // 6,553,600 B
  uint32_t* wfrag = (uint32_t*)(ws + 6553600);  //    98,304 B
  int* lenbuf = (int*)(ws + 6651904);           //       256 B
  float* Ee = (float*)(ws + 6652160);           //    10,816 B
  float* EeT = (float*)(ws + 6662976);          //    10,816 B
  float* fvec = (float*)(ws + 6673792);         //   262,144 B
  float* gvec = (float*)(ws + 6935936);         //   262,144 B
  float* Lf = (float*)(ws + 7198080);           //     4,096 B
  float* numpart = (float*)(ws + 7202176);      //     4,096 B

  prep_kernel<<<89, 256, 0, stream>>>(W, trans, mask, wfrag, lenbuf, Ee, EeT);
  emissions_kernel<<<(Bn * Sn) / 64, 256, 0, stream>>>(hidden, wfrag, bias,
                                                       lenbuf, em);
  scan_kernel<<<Bn * NCH * 2, 64, 0, stream>>>(em, startT, trans, Ee, EeT, tag,
                                               lenbuf, fvec, gvec, Lf, numpart);
  stitch_kernel<<<Bn, 64, 0, stream>>>(em, startT, endT, tag, lenbuf, fvec,
                                       gvec, Lf, numpart, out);
}

// Round 13
// 64.966 us; speedup vs baseline: 5.3524x; 5.3524x over previous
//
#include <hip/hip_runtime.h>
#include <cstdint>
#include <cstddef>

#define Bn 64
#define Sn 512
#define Hn 768
#define Tn 50
#define CH 32   // scan chunk length (steps)
#define NCH 16  // max chunks per sequence
#define BK 64

typedef short short8 __attribute__((ext_vector_type(8)));
typedef float floatx4 __attribute__((ext_vector_type(4)));

__device__ __forceinline__ uint32_t rne_bf16(float x) {
  uint32_t u = __float_as_uint(x);
  return (u + 0x7FFFu + ((u >> 16) & 1u)) >> 16;
}
__device__ __forceinline__ uint32_t pack2(float a, float b) {
  return rne_bf16(a) | (rne_bf16(b) << 16);
}
__device__ __forceinline__ float rdlane(float v, int i) {
  return __uint_as_float(__builtin_amdgcn_readlane(__float_as_uint(v), i));
}

// ------ Kernel 0: prep — lengths + W fragment pack + packed E tables ------
// EfwdP[i*64+j] = exp(trans[i][j]); EbwdP[i*64+j] = exp(trans[j][i]).
// Scan's one-time e[i] load (fixed i, lanes j) is one coalesced 256B line.
__global__ __launch_bounds__(256) void prep_kernel(
    const float* __restrict__ W, const float* __restrict__ trans,
    const int* __restrict__ mask, uint32_t* __restrict__ wfrag,
    int* __restrict__ lenbuf, float* __restrict__ EfwdP,
    float* __restrict__ EbwdP) {
  const int blk = blockIdx.x;
  const int tid = threadIdx.x;
  if (blk < 64) {
    if (tid < 64) {
      int s = 0;
      for (int t = tid; t < Sn; t += 64) s += mask[blk * Sn + t];
#pragma unroll
      for (int off = 1; off < 64; off <<= 1) s += __shfl_xor(s, off);
      if (tid == 0) lenbuf[blk] = s;
    }
    return;
  }
  if (blk == 88) {  // packed exp(trans) tables
    for (int gid = tid; gid < Tn * 64; gid += 256) {
      const int i = gid >> 6, j = gid & 63;
      EfwdP[gid] = (j < Tn) ? __expf(trans[i * Tn + j]) : 0.f;
      EbwdP[gid] = (j < Tn) ? __expf(trans[j * Tn + i]) : 0.f;
    }
    return;
  }
  const int gid = (blk - 64) * 256 + tid;  // [0, 6144)
  const int f = gid >> 6;                  // 0..95
  const int l = gid & 63;
  const int ks = f >> 2, nt = f & 3;
  const int col = nt * 16 + (l & 15);
  const int k0 = ks * 32 + (l >> 4) * 8;
  float v[8];
#pragma unroll
  for (int j = 0; j < 8; ++j)
    v[j] = (col < Tn) ? W[(size_t)(k0 + j) * Tn + col] : 0.f;
  uint4 d;
  d.x = pack2(v[0], v[1]);
  d.y = pack2(v[2], v[3]);
  d.z = pack2(v[4], v[5]);
  d.w = pack2(v[6], v[7]);
  ((uint4*)wfrag)[gid] = d;
}

// ------ Kernel 1: emissions via MFMA (r6 verbatim, (256,1)) ------
__global__ __launch_bounds__(256, 1) void emissions_kernel(
    const float* __restrict__ hidden, const uint32_t* __restrict__ wfrag,
    const float* __restrict__ bias, const int* __restrict__ lenbuf,
    float* __restrict__ em) {
  const int blk = blockIdx.x;
  const int bb = blk >> 3, cc = blk & 7;
  if (cc * 64 >= lenbuf[bb]) return;  // rows never read by CRF
  const int tid = threadIdx.x;
  const int lane = tid & 63;
  const int w = tid >> 6;
  const int g = lane >> 4;
  const int li = lane & 15;
  const int row0 = blk * 64;
  __shared__ char lds_raw[64 * 128];

  floatx4 acc[4];
#pragma unroll
  for (int nt = 0; nt < 4; ++nt) acc[nt] = (floatx4)0.f;

  const float* hbase = hidden + (size_t)row0 * Hn;
  const short8* wf = (const short8*)wfrag;

#define LOADCH(dst, ch)                                                      \
  _Pragma("unroll") for (int k = 0; k < 4; ++k) dst[k] =                     \
      *(const float4*)(hbase + (size_t)(w * 16 + 4 * k + g) * Hn + (ch)*BK + \
                       li * 4);
#define WRITELDS(src)                                                        \
  _Pragma("unroll") for (int k = 0; k < 4; ++k) {                            \
    const int r = w * 16 + 4 * k + g;                                        \
    const uint32_t b0 = pack2(src[k].x, src[k].y);                           \
    const uint32_t b1 = pack2(src[k].z, src[k].w);                           \
    const int byteoff = r * 128 + ((li * 8) ^ ((r & 7) << 4));               \
    *(uint2*)(lds_raw + byteoff) = make_uint2(b0, b1);                       \
  }
#define COMPUTE(ch)                                                          \
  _Pragma("unroll") for (int ks = 0; ks < 2; ++ks) {                         \
    const int r = w * 16 + li;                                               \
    const int kb = ks * 64 + g * 16;                                         \
    const short8 af =                                                        \
        *(const short8*)(lds_raw + r * 128 + (kb ^ ((r & 7) << 4)));         \
    const int ksg = (ch)*2 + ks;                                             \
    _Pragma("unroll") for (int nt = 0; nt < 4; ++nt) {                       \
      const short8 bf = wf[(ksg * 4 + nt) * 64 + lane];                      \
      acc[nt] =                                                              \
          __builtin_amdgcn_mfma_f32_16x16x32_bf16(af, bf, acc[nt], 0, 0, 0); \
    }                                                                        \
  }

  float4 pfA[4], pfB[4];
  LOADCH(pfA, 0)
  LOADCH(pfB, 1)
#pragma unroll
  for (int chp = 0; chp < Hn / BK / 2; ++chp) {
    const int ch = 2 * chp;
    WRITELDS(pfA)
    if (ch + 2 < Hn / BK) LOADCH(pfA, ch + 2)
    COMPUTE(ch)
    WRITELDS(pfB)
    if (ch + 3 < Hn / BK) LOADCH(pfB, ch + 3)
    COMPUTE(ch + 1)
  }
#undef LOADCH
#undef WRITELDS
#undef COMPUTE

#pragma unroll
  for (int nt = 0; nt < 4; ++nt) {
    const int col = nt * 16 + li;
    if (col < Tn) {
      const float bs = bias[col];
#pragma unroll
      for (int r = 0; r < 4; ++r) {
        const int row = row0 + w * 16 + g * 4 + r;
        em[(size_t)row * Tn + col] = acc[nt][r] + bs;
      }
    }
  }
}

// ------ Kernel 2: chunked scans — (64,1) + asm-pinned e[] ------
// r12 measured VGPR=48: the compiler re-sinks the 50 loop-invariant e-loads
// into the step loop (50 reloads x 32 steps). The pin makes the asm output
// the only source of e[i]: loads must execute once; re-sinking impossible.
// (64,1) gives cap-512 so the 50 pinned values + state fit without spill —
// r4/r5's pins failed only because their cap was ~64 (no min-waves arg).
__global__ __launch_bounds__(64, 1) void scan_kernel(
    const float* __restrict__ em, const float* __restrict__ startT,
    const float* __restrict__ trans, const float* __restrict__ EfwdP,
    const float* __restrict__ EbwdP, const int* __restrict__ tag,
    const int* __restrict__ lenbuf, float* __restrict__ fvec,
    float* __restrict__ gvec, float* __restrict__ Lf,
    float* __restrict__ numpart) {
  const int blk = blockIdx.x;
  const int b = blk >> 5;
  const int c = (blk >> 1) & (NCH - 1);
  const int dir = blk & 1;  // 0 = forward (f), 1 = backward (g)
  const int len = lenbuf[b];
  const int t0 = 1 + c * CH;
  if (t0 >= len) return;
  if (dir && c == 0) return;
  const int t1 = (t0 + CH < len) ? t0 + CH : len;
  const int L = t1 - t0;
  const int lane = threadIdx.x;
  const int jc = lane < Tn ? lane : 0;
  const bool live = lane < Tn;
  const float* emb = em + (size_t)b * Sn * Tn;

  if (!dir) {  // chunk numerator partial; lane = timestep
    float npv = 0.f;
    if (lane < L) {
      const int t = t0 + lane;
      const int tp = tag[b * Sn + t - 1], tc = tag[b * Sn + t];
      npv = trans[tp * Tn + tc] + emb[(size_t)t * Tn + tc];
    }
#pragma unroll
    for (int off = 1; off < 64; off <<= 1) npv += __shfl_xor(npv, off);
    if (lane == 0) numpart[b * NCH + c] = npv;
  }

  // e[i]: coalesced one-time load (fixed i, lanes jc consecutive) + pin.
  const float* ebase = dir ? EbwdP : EfwdP;
  float e[Tn];
#pragma unroll
  for (int i = 0; i < Tn; ++i) {
    e[i] = ebase[i * 64 + jc];
    asm volatile("" : "+v"(e[i]));  // register-resident by construction
  }

  float Cacc = 0.f;
  float q;
  if (!dir)
    q = live ? (c == 0 ? __expf(startT[jc] + emb[jc]) : 1.f) : 0.f;
  else
    q = live ? 1.f : 0.f;

#define T_OF(k) (dir ? (t1 - 1 - (k)) : (t0 + (k)))
  float ld1 = emb[(size_t)T_OF(0) * Tn + jc];
  const float ld2 = emb[(size_t)T_OF(L > 1 ? 1 : 0) * Tn + jc];
  float ee = live ? __expf(ld1) : 0.f;
  ld1 = ld2;

  for (int k = 0; k < L; ++k) {
    const float ee_cur = ee;
    const int kn = (k + 2 < L) ? k + 2 : L - 1;
    const float ldn = emb[(size_t)T_OF(kn) * Tn + jc];
    ee = live ? __expf(ld1) : 0.f;
    ld1 = ldn;

    const float x = dir ? ee_cur * q : q;  // g pre-multiplies by D_t
    float s0 = 0.f, s1 = 0.f, s2 = 0.f, s3 = 0.f;
#pragma unroll
    for (int i = 0; i < 48; i += 4) {
      s0 = fmaf(rdlane(x, i + 0), e[i + 0], s0);
      s1 = fmaf(rdlane(x, i + 1), e[i + 1], s1);
      s2 = fmaf(rdlane(x, i + 2), e[i + 2], s2);
      s3 = fmaf(rdlane(x, i + 3), e[i + 3], s3);
    }
    s0 = fmaf(rdlane(x, 48), e[48], s0);
    s1 = fmaf(rdlane(x, 49), e[49], s1);
    const float s = (s0 + s1) + (s2 + s3);
    q = dir ? s : ee_cur * s;  // f post-multiplies by D_t

    if ((k & 7) == 7) {
      float M = q;
#pragma unroll
      for (int off = 1; off < 64; off <<= 1) M = fmaxf(M, __shfl_xor(M, off));
      const float r = __builtin_amdgcn_rcpf(M);
      q *= r;
      Cacc -= __logf(r);
    }
  }
#undef T_OF

  float M = q;
#pragma unroll
  for (int off = 1; off < 64; off <<= 1) M = fmaxf(M, __shfl_xor(M, off));
  const float r = __builtin_amdgcn_rcpf(M);
  const float qn = live ? q * r : 0.f;
  Cacc -= __logf(r);
  if (dir) {
    gvec[((size_t)b * NCH + c) * 64 + lane] = qn;
  } else {
    fvec[((size_t)b * NCH + c) * 64 + lane] = qn;
    if (lane == 0) Lf[b * NCH + c] = Cacc;
  }
}

// ------ Kernel 3: stitch — rank-1 chain + numerator (r6 verbatim) ------
__global__ __launch_bounds__(64) void stitch_kernel(
    const float* __restrict__ em, const float* __restrict__ startT,
    const float* __restrict__ endT, const int* __restrict__ tag,
    const int* __restrict__ lenbuf, const float* __restrict__ fvec,
    const float* __restrict__ gvec, const float* __restrict__ Lf,
    const float* __restrict__ numpart, float* __restrict__ out) {
  const int b = blockIdx.x;
  const int lane = threadIdx.x;
  const int len = lenbuf[b];
  const int C = (len - 1 + CH - 1) / CH;
  const int jc = lane < Tn ? lane : 0;
  const bool live = lane < Tn;
  const float* emb = em + (size_t)b * Sn * Tn;

  float np = (lane < C) ? numpart[b * NCH + lane] : 0.f;
#pragma unroll
  for (int off = 1; off < 64; off <<= 1) np += __shfl_xor(np, off);
  const int tg0 = tag[b * Sn];
  const int tgl = tag[b * Sn + len - 1];
  np += startT[tg0] + emb[tg0] + endT[tgl];

  float den;
  if (C == 0) {  // len == 1
    float v = live ? (startT[jc] + emb[jc] + endT[jc]) : -INFINITY;
    float M = v;
#pragma unroll
    for (int off = 1; off < 64; off <<= 1) M = fmaxf(M, __shfl_xor(M, off));
    float s = __expf(v - M);
#pragma unroll
    for (int off = 1; off < 64; off <<= 1) s += __shfl_xor(s, off);
    den = M + __logf(s);
  } else {
    const float ev = live ? __expf(endT[jc]) : 0.f;
    float d = fvec[((size_t)b * NCH + C - 1) * 64 + lane] * ev;
#pragma unroll
    for (int off = 1; off < 64; off <<= 1) d += __shfl_xor(d, off);
    den = Lf[b * NCH + C - 1] + __logf(d);
    for (int c2 = 1; c2 < C; ++c2) {
      const float g = gvec[((size_t)b * NCH + c2) * 64 + lane];
      const float f = fvec[((size_t)b * NCH + c2 - 1) * 64 + lane];
      float dot = g * f;
      float gs = g;
#pragma unroll
      for (int off = 1; off < 64; off <<= 1) {
        dot += __shfl_xor(dot, off);
        gs += __shfl_xor(gs, off);
      }
      den += Lf[b * NCH + c2 - 1] + __logf(dot) - __logf(gs);
    }
  }
  if (lane == 0) out[b] = den - np;
}

extern "C" void kernel_launch(void* const* d_in, const int* in_sizes, int n_in,
                              void* d_out, int out_size, void* d_ws,
                              size_t ws_size, hipStream_t stream) {
  const float* hidden = (const float*)d_in[0];
  const float* W = (const float*)d_in[1];
  const float* bias = (const float*)d_in[2];
  const float* startT = (const float*)d_in[3];
  const float* endT = (const float*)d_in[4];
  const float* trans = (const float*)d_in[5];
  const int* tag = (const int*)d_in[6];
  const int* mask = (const int*)d_in[7];
  float* out = (float*)d_out;

  // ws layout (16B-aligned offsets)
  char* ws = (char*)d_ws;
  float* em = (float*)ws;                       // 6,553,600 B
  uint32_t* wfrag = (uint32_t*)(ws + 6553600);  //    98,304 B
  int* lenbuf = (int*)(ws + 6651904);           //       256 B
  float* EfwdP = (float*)(ws + 6652160);        //    12,800 B
  float* EbwdP = (float*)(ws + 6664960);        //    12,800 B
  float* fvec = (float*)(ws + 6677760);         //   262,144 B
  float* gvec = (float*)(ws + 6939904);         //   262,144 B
  float* Lf = (float*)(ws + 7202048);           //     4,096 B
  float* numpart = (float*)(ws + 7206144);      //     4,096 B

  prep_kernel<<<89, 256, 0, stream>>>(W, trans, mask, wfrag, lenbuf, EfwdP,
                                      EbwdP);
  emissions_kernel<<<(Bn * Sn) / 64, 256, 0, stream>>>(hidden, wfrag, bias,
                                                       lenbuf, em);
  scan_kernel<<<Bn * NCH * 2, 64, 0, stream>>>(em, startT, trans, EfwdP, EbwdP,
                                               tag, lenbuf, fvec, gvec, Lf,
                                               numpart);
  stitch_kernel<<<Bn, 64, 0, stream>>>(em, startT, endT, tag, lenbuf, fvec,
                                       gvec, Lf, numpart, out);
}

// Round 14
// 54.586 us; speedup vs baseline: 6.3702x; 1.1902x over previous
//
#include <hip/hip_runtime.h>
#include <cstdint>
#include <cstddef>

#define Bn 64
#define Sn 512
#define Hn 768
#define Tn 50
#define CH 32   // scan chunk length (steps)
#define NCH 16  // max chunks per sequence
#define EP 52   // padded row stride for exp(trans) tables (208B, 16B-aligned)
#define BK 64

typedef short short8 __attribute__((ext_vector_type(8)));
typedef float floatx4 __attribute__((ext_vector_type(4)));

__device__ __forceinline__ uint32_t rne_bf16(float x) {
  uint32_t u = __float_as_uint(x);
  return (u + 0x7FFFu + ((u >> 16) & 1u)) >> 16;
}
__device__ __forceinline__ uint32_t pack2(float a, float b) {
  return rne_bf16(a) | (rne_bf16(b) << 16);
}
__device__ __forceinline__ float rdlane(float v, int i) {
  return __uint_as_float(__builtin_amdgcn_readlane(__float_as_uint(v), i));
}

// ------ Kernel 0: prep — r6 verbatim (EP-strided exp tables) ------
// NOTE: EP-strided (per-lane contiguous row) is deliberate: e[] is reloaded
// in the scan loop regardless of intent (r12: VGPR=48), and this layout
// reloads as ~13 b128/step vs 50 dwords/step for the packed layout
// (r11/r13 regressions). Do not "fix" to packed again.
__global__ __launch_bounds__(256) void prep_kernel(
    const float* __restrict__ W, const float* __restrict__ trans,
    const int* __restrict__ mask, uint32_t* __restrict__ wfrag,
    int* __restrict__ lenbuf, float* __restrict__ Ee,
    float* __restrict__ EeT) {
  const int blk = blockIdx.x;
  const int tid = threadIdx.x;
  if (blk < 64) {
    if (tid < 64) {
      int s = 0;
      for (int t = tid; t < Sn; t += 64) s += mask[blk * Sn + t];
#pragma unroll
      for (int off = 1; off < 64; off <<= 1) s += __shfl_xor(s, off);
      if (tid == 0) lenbuf[blk] = s;
    }
    return;
  }
  if (blk == 88) {  // exp(trans) and transpose, padded stride EP
    for (int gid = tid; gid < Tn * Tn; gid += 256) {
      const int r = gid / Tn, cl = gid - r * Tn;
      const float v = __expf(trans[gid]);
      Ee[r * EP + cl] = v;
      EeT[cl * EP + r] = v;
    }
    return;
  }
  const int gid = (blk - 64) * 256 + tid;  // [0, 6144)
  const int f = gid >> 6;                  // 0..95
  const int l = gid & 63;
  const int ks = f >> 2, nt = f & 3;
  const int col = nt * 16 + (l & 15);
  const int k0 = ks * 32 + (l >> 4) * 8;
  float v[8];
#pragma unroll
  for (int j = 0; j < 8; ++j)
    v[j] = (col < Tn) ? W[(size_t)(k0 + j) * Tn + col] : 0.f;
  uint4 d;
  d.x = pack2(v[0], v[1]);
  d.y = pack2(v[2], v[3]);
  d.z = pack2(v[4], v[5]);
  d.w = pack2(v[6], v[7]);
  ((uint4*)wfrag)[gid] = d;
}

// ------ Kernel 1: emissions via MFMA — 128-thread blocks, 32 rows ------
// Reshape only (per-wave code byte-identical to r6): 1024 blocks x 2 waves
// -> ~4 blocks/CU co-resident (vs 1-2) -> more independent HBM streams for
// the staging-bound phase; finer 32-row length gate. (128,1) keeps the
// relaxed VGPR cap (no regalloc change — r10's failure was the cap).
__global__ __launch_bounds__(128, 1) void emissions_kernel(
    const float* __restrict__ hidden, const uint32_t* __restrict__ wfrag,
    const float* __restrict__ bias, const int* __restrict__ lenbuf,
    float* __restrict__ em) {
  const int blk = blockIdx.x;
  const int bb = blk >> 4, cc = blk & 15;
  if (cc * 32 >= lenbuf[bb]) return;  // rows never read by CRF
  const int tid = threadIdx.x;
  const int lane = tid & 63;
  const int w = tid >> 6;  // 0..1
  const int g = lane >> 4;
  const int li = lane & 15;
  const int row0 = blk * 32;
  __shared__ char lds_raw[32 * 128];

  floatx4 acc[4];
#pragma unroll
  for (int nt = 0; nt < 4; ++nt) acc[nt] = (floatx4)0.f;

  const float* hbase = hidden + (size_t)row0 * Hn;
  const short8* wf = (const short8*)wfrag;

#define LOADCH(dst, ch)                                                      \
  _Pragma("unroll") for (int k = 0; k < 4; ++k) dst[k] =                     \
      *(const float4*)(hbase + (size_t)(w * 16 + 4 * k + g) * Hn + (ch)*BK + \
                       li * 4);
#define WRITELDS(src)                                                        \
  _Pragma("unroll") for (int k = 0; k < 4; ++k) {                            \
    const int r = w * 16 + 4 * k + g;                                        \
    const uint32_t b0 = pack2(src[k].x, src[k].y);                           \
    const uint32_t b1 = pack2(src[k].z, src[k].w);                           \
    const int byteoff = r * 128 + ((li * 8) ^ ((r & 7) << 4));               \
    *(uint2*)(lds_raw + byteoff) = make_uint2(b0, b1);                       \
  }
#define COMPUTE(ch)                                                          \
  _Pragma("unroll") for (int ks = 0; ks < 2; ++ks) {                         \
    const int r = w * 16 + li;                                               \
    const int kb = ks * 64 + g * 16;                                         \
    const short8 af =                                                        \
        *(const short8*)(lds_raw + r * 128 + (kb ^ ((r & 7) << 4)));         \
    const int ksg = (ch)*2 + ks;                                             \
    _Pragma("unroll") for (int nt = 0; nt < 4; ++nt) {                       \
      const short8 bf = wf[(ksg * 4 + nt) * 64 + lane];                      \
      acc[nt] =                                                              \
          __builtin_amdgcn_mfma_f32_16x16x32_bf16(af, bf, acc[nt], 0, 0, 0); \
    }                                                                        \
  }

  float4 pfA[4], pfB[4];
  LOADCH(pfA, 0)
  LOADCH(pfB, 1)
#pragma unroll
  for (int chp = 0; chp < Hn / BK / 2; ++chp) {
    const int ch = 2 * chp;
    WRITELDS(pfA)
    if (ch + 2 < Hn / BK) LOADCH(pfA, ch + 2)
    COMPUTE(ch)
    WRITELDS(pfB)
    if (ch + 3 < Hn / BK) LOADCH(pfB, ch + 3)
    COMPUTE(ch + 1)
  }
#undef LOADCH
#undef WRITELDS
#undef COMPUTE

#pragma unroll
  for (int nt = 0; nt < 4; ++nt) {
    const int col = nt * 16 + li;
    if (col < Tn) {
      const float bs = bias[col];
#pragma unroll
      for (int r = 0; r < 4; ++r) {
        const int row = row0 + w * 16 + g * 4 + r;
        em[(size_t)row * Tn + col] = acc[nt][r] + bs;
      }
    }
  }
}

// ------ Kernel 2: chunked scans — r6 VERBATIM (proven 19.2 us) ------
__global__ __launch_bounds__(64, 1) void scan_kernel(
    const float* __restrict__ em, const float* __restrict__ startT,
    const float* __restrict__ trans, const float* __restrict__ Ee,
    const float* __restrict__ EeT, const int* __restrict__ tag,
    const int* __restrict__ lenbuf, float* __restrict__ fvec,
    float* __restrict__ gvec, float* __restrict__ Lf,
    float* __restrict__ numpart) {
  const int blk = blockIdx.x;
  const int b = blk >> 5;
  const int c = (blk >> 1) & (NCH - 1);
  const int dir = blk & 1;  // 0 = forward (f), 1 = backward (g)
  const int len = lenbuf[b];
  const int t0 = 1 + c * CH;
  if (t0 >= len) return;
  if (dir && c == 0) return;
  const int t1 = (t0 + CH < len) ? t0 + CH : len;
  const int L = t1 - t0;
  const int lane = threadIdx.x;
  const int jc = lane < Tn ? lane : 0;
  const bool live = lane < Tn;
  const float* emb = em + (size_t)b * Sn * Tn;

  if (!dir) {  // chunk numerator partial; lane = timestep
    float npv = 0.f;
    if (lane < L) {
      const int t = t0 + lane;
      const int tp = tag[b * Sn + t - 1], tc = tag[b * Sn + t];
      npv = trans[tp * Tn + tc] + emb[(size_t)t * Tn + tc];
    }
#pragma unroll
    for (int off = 1; off < 64; off <<= 1) npv += __shfl_xor(npv, off);
    if (lane == 0) numpart[b * NCH + c] = npv;
  }

  // e[i]: f needs E[i][jc] = EeT row jc; g needs E[jc][i] = Ee row jc.
  const float* ebase = (dir ? Ee : EeT) + jc * EP;
  float e[Tn];
#pragma unroll
  for (int i = 0; i < Tn; ++i) e[i] = ebase[i];

  float Cacc = 0.f;
  float q;
  if (!dir)
    q = live ? (c == 0 ? __expf(startT[jc] + emb[jc]) : 1.f) : 0.f;
  else
    q = live ? 1.f : 0.f;

#define T_OF(k) (dir ? (t1 - 1 - (k)) : (t0 + (k)))
  float ld1 = emb[(size_t)T_OF(0) * Tn + jc];
  const float ld2 = emb[(size_t)T_OF(L > 1 ? 1 : 0) * Tn + jc];
  float ee = live ? __expf(ld1) : 0.f;
  ld1 = ld2;

  for (int k = 0; k < L; ++k) {
    const float ee_cur = ee;
    const int kn = (k + 2 < L) ? k + 2 : L - 1;
    const float ldn = emb[(size_t)T_OF(kn) * Tn + jc];
    ee = live ? __expf(ld1) : 0.f;
    ld1 = ldn;

    const float x = dir ? ee_cur * q : q;  // g pre-multiplies by D_t
    float s0 = 0.f, s1 = 0.f, s2 = 0.f, s3 = 0.f;
#pragma unroll
    for (int i = 0; i < 48; i += 4) {
      s0 = fmaf(rdlane(x, i + 0), e[i + 0], s0);
      s1 = fmaf(rdlane(x, i + 1), e[i + 1], s1);
      s2 = fmaf(rdlane(x, i + 2), e[i + 2], s2);
      s3 = fmaf(rdlane(x, i + 3), e[i + 3], s3);
    }
    s0 = fmaf(rdlane(x, 48), e[48], s0);
    s1 = fmaf(rdlane(x, 49), e[49], s1);
    const float s = (s0 + s1) + (s2 + s3);
    q = dir ? s : ee_cur * s;  // f post-multiplies by D_t

    if ((k & 7) == 7) {
      float M = q;
#pragma unroll
      for (int off = 1; off < 64; off <<= 1) M = fmaxf(M, __shfl_xor(M, off));
      const float r = __builtin_amdgcn_rcpf(M);
      q *= r;
      Cacc -= __logf(r);
    }
  }
#undef T_OF

  float M = q;
#pragma unroll
  for (int off = 1; off < 64; off <<= 1) M = fmaxf(M, __shfl_xor(M, off));
  const float r = __builtin_amdgcn_rcpf(M);
  const float qn = live ? q * r : 0.f;
  Cacc -= __logf(r);
  if (dir) {
    gvec[((size_t)b * NCH + c) * 64 + lane] = qn;
  } else {
    fvec[((size_t)b * NCH + c) * 64 + lane] = qn;
    if (lane == 0) Lf[b * NCH + c] = Cacc;
  }
}

// ------ Kernel 3: stitch — r6 verbatim ------
__global__ __launch_bounds__(64) void stitch_kernel(
    const float* __restrict__ em, const float* __restrict__ startT,
    const float* __restrict__ endT, const int* __restrict__ tag,
    const int* __restrict__ lenbuf, const float* __restrict__ fvec,
    const float* __restrict__ gvec, const float* __restrict__ Lf,
    const float* __restrict__ numpart, float* __restrict__ out) {
  const int b = blockIdx.x;
  const int lane = threadIdx.x;
  const int len = lenbuf[b];
  const int C = (len - 1 + CH - 1) / CH;
  const int jc = lane < Tn ? lane : 0;
  const bool live = lane < Tn;
  const float* emb = em + (size_t)b * Sn * Tn;

  float np = (lane < C) ? numpart[b * NCH + lane] : 0.f;
#pragma unroll
  for (int off = 1; off < 64; off <<= 1) np += __shfl_xor(np, off);
  const int tg0 = tag[b * Sn];
  const int tgl = tag[b * Sn + len - 1];
  np += startT[tg0] + emb[tg0] + endT[tgl];

  float den;
  if (C == 0) {  // len == 1
    float v = live ? (startT[jc] + emb[jc] + endT[jc]) : -INFINITY;
    float M = v;
#pragma unroll
    for (int off = 1; off < 64; off <<= 1) M = fmaxf(M, __shfl_xor(M, off));
    float s = __expf(v - M);
#pragma unroll
    for (int off = 1; off < 64; off <<= 1) s += __shfl_xor(s, off);
    den = M + __logf(s);
  } else {
    const float ev = live ? __expf(endT[jc]) : 0.f;
    float d = fvec[((size_t)b * NCH + C - 1) * 64 + lane] * ev;
#pragma unroll
    for (int off = 1; off < 64; off <<= 1) d += __shfl_xor(d, off);
    den = Lf[b * NCH + C - 1] + __logf(d);
    for (int c2 = 1; c2 < C; ++c2) {
      const float g = gvec[((size_t)b * NCH + c2) * 64 + lane];
      const float f = fvec[((size_t)b * NCH + c2 - 1) * 64 + lane];
      float dot = g * f;
      float gs = g;
#pragma unroll
      for (int off = 1; off < 64; off <<= 1) {
        dot += __shfl_xor(dot, off);
        gs += __shfl_xor(gs, off);
      }
      den += Lf[b * NCH + c2 - 1] + __logf(dot) - __logf(gs);
    }
  }
  if (lane == 0) out[b] = den - np;
}

extern "C" void kernel_launch(void* const* d_in, const int* in_sizes, int n_in,
                              void* d_out, int out_size, void* d_ws,
                              size_t ws_size, hipStream_t stream) {
  const float* hidden = (const float*)d_in[0];
  const float* W = (const float*)d_in[1];
  const float* bias = (const float*)d_in[2];
  const float* startT = (const float*)d_in[3];
  const float* endT = (const float*)d_in[4];
  const float* trans = (const float*)d_in[5];
  const int* tag = (const int*)d_in[6];
  const int* mask = (const int*)d_in[7];
  float* out = (float*)d_out;

  // ws layout (16B-aligned offsets) — r6 layout
  char* ws = (char*)d_ws;
  float* em = (float*)ws;                       // 6,553,600 B
  uint32_t* wfrag = (uint32_t*)(ws + 6553600);  //    98,304 B
  int* lenbuf = (int*)(ws + 6651904);           //       256 B
  float* Ee = (float*)(ws + 6652160);           //    10,816 B
  float* EeT = (float*)(ws + 6662976);          //    10,816 B
  float* fvec = (float*)(ws + 6673792);         //   262,144 B
  float* gvec = (float*)(ws + 6935936);         //   262,144 B
  float* Lf = (float*)(ws + 7198080);           //     4,096 B
  float* numpart = (float*)(ws + 7202176);      //     4,096 B

  prep_kernel<<<89, 256, 0, stream>>>(W, trans, mask, wfrag, lenbuf, Ee, EeT);
  emissions_kernel<<<(Bn * Sn) / 32, 128, 0, stream>>>(hidden, wfrag, bias,
                                                       lenbuf, em);
  scan_kernel<<<Bn * NCH * 2, 64, 0, stream>>>(em, startT, trans, Ee, EeT, tag,
                                               lenbuf, fvec, gvec, Lf, numpart);
  stitch_kernel<<<Bn, 64, 0, stream>>>(em, startT, endT, tag, lenbuf, fvec,
                                       gvec, Lf, numpart, out);
}